// Round 16
// baseline (287.923 us; speedup 1.0000x reference)
//
#include <hip/hip_runtime.h>
#include <hip/hip_bf16.h>

typedef unsigned short u16;
typedef unsigned int   u32;
typedef __bf16 bf16x8 __attribute__((ext_vector_type(8)));
typedef float  f32x4  __attribute__((ext_vector_type(4)));
typedef u16    u16x8  __attribute__((ext_vector_type(8)));
typedef u32    u32x2  __attribute__((ext_vector_type(2)));

#define GAS __attribute__((address_space(1)))
#define LAS __attribute__((address_space(3)))

__device__ __forceinline__ void gload_lds16(const void* g, void* lds) {
  __builtin_amdgcn_global_load_lds((GAS u32*)g, (LAS u32*)lds, 16, 0, 0);
}

__device__ __forceinline__ u16 f2bf(float f) {
  union { float f; u32 u; } v; v.f = f;
  u32 r = v.u + 0x7FFFu + ((v.u >> 16) & 1u);   // round-to-nearest-even
  return (u16)(r >> 16);
}

__device__ __forceinline__ u32 cvtpk_bf16(float lo, float hi) {
  u32 r;
  asm("v_cvt_pk_bf16_f32 %0, %1, %2" : "=v"(r) : "v"(lo), "v"(hi));
  return r;
}

template <int N> __device__ __forceinline__ void wait_vmcnt() {
  if constexpr (N == 3)      asm volatile("s_waitcnt vmcnt(3)" ::: "memory");
  else if constexpr (N == 4) asm volatile("s_waitcnt vmcnt(4)" ::: "memory");
  else                       asm volatile("s_waitcnt vmcnt(0)" ::: "memory");
}

// ---------------- elementwise cast x: f32 -> bf16 (8 elems/thread) ----------------
__global__ __launch_bounds__(256) void cast_x_kernel(const float* __restrict__ x,
                                                     u16* __restrict__ xb) {
  int i = (blockIdx.x * 256 + threadIdx.x) * 8;
  float4 a = *(const float4*)(x + i);
  float4 b = *(const float4*)(x + i + 4);
  u16x8 o;
  o[0] = f2bf(a.x); o[1] = f2bf(a.y); o[2] = f2bf(a.z); o[3] = f2bf(a.w);
  o[4] = f2bf(b.x); o[5] = f2bf(b.y); o[6] = f2bf(b.z); o[7] = f2bf(b.w);
  *(u16x8*)(xb + i) = o;
}

// ------------- fused transpose-cast: 4x W[k][n] f32 -> WT[n][k] bf16 (x scale) ----
struct TC4 {
  const float* W[4];
  u16* D[4];
  float s[4];
};
__global__ __launch_bounds__(256) void transcast4(TC4 p) {
  __shared__ float t[32][33];
  const int tx = threadIdx.x, ty = threadIdx.y;      // 32 x 8
  const int z = blockIdx.z;
  const float* __restrict__ W = p.W[z];
  u16* __restrict__ WT = p.D[z];
  const float scale = p.s[z];
  const int c0 = blockIdx.x * 32, r0 = blockIdx.y * 32;
#pragma unroll
  for (int i = 0; i < 4; ++i)
    t[ty + i * 8][tx] = W[(r0 + ty + i * 8) * 2048 + c0 + tx];
  __syncthreads();
#pragma unroll
  for (int i = 0; i < 4; ++i)
    WT[(c0 + ty + i * 8) * 2048 + r0 + tx] = f2bf(t[tx][ty + i * 8] * scale);
}

// ---------------- GEMM BMxBN, BK=64, 8 waves, 4-phase counted-vmcnt pipeline ------
// R15 geometry + m201-style phase split: each ks-group is TWO barrier-bounded
// phases of 16 MFMA ({reads, stage-issue, MFMA} | bar | {reads, stage-issue,
// MFMA}) -> 4 phases/K-tile. Extra barrier is uniform -> race-free; vmcnt ledger
// unchanged (at each ks-top: outstanding 2(CA+CB), oldest CA+CB = this group's
// operands). Phase-split creates the wave role-diversity that makes T2 swizzle
// + T5 setprio pay (regime-gate: both null at 2-phase, +18-39% at 8-phase).
template <int OUTF32, int BM, int BN, int WM, int WN>
__global__ __launch_bounds__(512, 2) void gemm256(
    const u16* __restrict__ A, const u16* __restrict__ B,
    float* __restrict__ Cf, u16* __restrict__ Cb, const float* __restrict__ bias,
    int M, int N, int K, int lda, int ldb, int ldc) {
  constexpr int PM = BM / WM, PN = BN / WN;    // per-wave output
  constexpr int MI = PM / 16, NI = PN / 16;    // acc tile counts
  constexpr int CA = BM / 128, CB = BN / 128;  // staging chunks per thread
  __shared__ alignas(16) u16 lds[2][2][(BM + BN) * 32];

  const int tid = threadIdx.x;                 // 0..511
  const int lane = tid & 63, wave = tid >> 6;
  const int wm = wave / WN, wn = wave % WN;
  const int r15 = lane & 15, g = lane >> 4;

  const int gx = gridDim.x;
  const int nwg = gx * gridDim.y;
  const int orig = blockIdx.y * gx + blockIdx.x;
  const int wg = (orig & 7) * (nwg >> 3) + (orig >> 3);
  const int tm = (wg % gx) * BM, tn = (wg / gx) * BN;

  int aoff[CA], boff[CB];
#pragma unroll
  for (int i = 0; i < CA; ++i) {
    int c = i * 512 + tid, row = c >> 2, ch = c & 3;
    aoff[i] = (tm + row) * lda + (ch ^ ((row >> 1) & 3)) * 8;
  }
#pragma unroll
  for (int i = 0; i < CB; ++i) {
    int c = i * 512 + tid, row = c >> 2, ch = c & 3;
    boff[i] = (tn + row) * ldb + (ch ^ ((row >> 1) & 3)) * 8;
  }

  auto stageA = [&](int kofs, int buf, int ks) {
#pragma unroll
    for (int i = 0; i < CA; ++i)
      gload_lds16(A + aoff[i] + kofs,
                  (char*)&lds[buf][ks][0] + (i * 8 + wave) * 1024);
  };
  auto stageB = [&](int kofs, int buf, int ks) {
#pragma unroll
    for (int i = 0; i < CB; ++i)
      gload_lds16(B + boff[i] + kofs,
                  (char*)&lds[buf][ks][BM * 32] + (i * 8 + wave) * 1024);
  };

  f32x4 acc[MI][NI] = {};
  const int NT = K / 64;
  const int fsw = (r15 >> 1) & 3;              // fragment-read chunk swizzle

  stageA(0, 0, 0);  stageB(0, 0, 0);
  stageA(32, 0, 1); stageB(32, 0, 1);

  for (int t = 0; t < NT; ++t) {
    const int cur = t & 1, nxt = cur ^ 1;
    const int kn = (t + 1 < NT) ? (t + 1) * 64 : 0;   // last tile: dummy restage
#pragma unroll
    for (int ks = 0; ks < 2; ++ks) {
      // ---- phase 1: publish this ks-group, low-half MFMA ----
      wait_vmcnt<CA + CB>();                   // drain this group's operands only
      __builtin_amdgcn_s_barrier();
      __builtin_amdgcn_sched_barrier(0);

      const char* Ab = (const char*)&lds[cur][ks][0];
      const char* Bb = (const char*)&lds[cur][ks][BM * 32];
      bf16x8 bfr[NI], af[MI / 2];
#pragma unroll
      for (int ni = 0; ni < NI; ++ni)
        bfr[ni] = *(const bf16x8*)(Bb + (wn * PN + ni * 16 + r15) * 64 +
                                   ((g ^ fsw) << 4));
#pragma unroll
      for (int mi = 0; mi < MI / 2; ++mi)
        af[mi] = *(const bf16x8*)(Ab + (wm * PM + mi * 16 + r15) * 64 +
                                  ((g ^ fsw) << 4));

      stageA(kn + ks * 32, nxt, ks);

      __builtin_amdgcn_s_setprio(1);
#pragma unroll
      for (int mi = 0; mi < MI / 2; ++mi)
#pragma unroll
        for (int ni = 0; ni < NI; ++ni)
          acc[mi][ni] = __builtin_amdgcn_mfma_f32_16x16x32_bf16(af[mi], bfr[ni],
                                                                acc[mi][ni], 0, 0, 0);
      __builtin_amdgcn_s_setprio(0);

      // ---- phase 2: high-half MFMA (wave role-split alignment) ----
      __builtin_amdgcn_s_barrier();
      __builtin_amdgcn_sched_barrier(0);

#pragma unroll
      for (int mi = 0; mi < MI / 2; ++mi)
        af[mi] = *(const bf16x8*)(Ab + (wm * PM + (mi + MI / 2) * 16 + r15) * 64 +
                                  ((g ^ fsw) << 4));

      stageB(kn + ks * 32, nxt, ks);

      __builtin_amdgcn_s_setprio(1);
#pragma unroll
      for (int mi = 0; mi < MI / 2; ++mi)
#pragma unroll
        for (int ni = 0; ni < NI; ++ni)
          acc[mi + MI / 2][ni] = __builtin_amdgcn_mfma_f32_16x16x32_bf16(
              af[mi], bfr[ni], acc[mi + MI / 2][ni], 0, 0, 0);
      __builtin_amdgcn_s_setprio(0);
    }
  }

  // epilogue
#pragma unroll
  for (int mi = 0; mi < MI; ++mi)
#pragma unroll
    for (int ni = 0; ni < NI; ++ni)
#pragma unroll
      for (int r = 0; r < 4; ++r) {
        int m = tm + wm * PM + mi * 16 + g * 4 + r;
        int n = tn + wn * PN + ni * 16 + r15;
        float v = acc[mi][ni][r];
        if (OUTF32) Cf[(size_t)m * ldc + n] = v + bias[n];
        else        Cb[(size_t)m * ldc + n] = f2bf(v);
      }
}

// ---------------- flash attention: 8 waves, KVBLK=64, TWO-barrier pipeline --------
// (exact R8/R9/R14/R15 state — passed four times at ~126 us. DO NOT TOUCH.)
// QK:  [B*S][4096] bf16 rows = {Q[h][d], K_scaled[h][d]}  (K pre-scaled by C2)
// VtG: [2048][4096] bf16 = V^T, row (h*128+d), col (b*2048+s)
// O:   [B*S][2048] bf16
__global__ __launch_bounds__(512, 4) void attn_kernel(const u16* __restrict__ QK,
                                                      const u16* __restrict__ VtG,
                                                      u16* __restrict__ O) {
  __shared__ alignas(16) u16 Ks[2][64 * 128];   // 16KB each
  __shared__ alignas(16) u16 Vs[2][128 * 64];   // 16KB each

  const int tid = threadIdx.x, lane = tid & 63, wave = tid >> 6;
  const int r15 = lane & 15, g = lane >> 4;

  const int orig = (blockIdx.z * 16 + blockIdx.y) * 16 + blockIdx.x;  // 512 wgs
  const int wg = (orig & 7) * 64 + (orig >> 3);
  const int qb = wg & 15, h = (wg >> 4) & 15, b = wg >> 8;

  const u16* Qp = QK + (size_t)b * 2048 * 4096 + h * 128;
  const u16* Kp = Qp + 2048;
  const u16* Vp = VtG + (size_t)(h * 128) * 4096 + b * 2048;

  const int qrow = qb * 128 + wave * 16 + r15;
  bf16x8 qf[4];
#pragma unroll
  for (int kc = 0; kc < 4; ++kc)
    qf[kc] = *(const bf16x8*)(Qp + (size_t)qrow * 4096 + kc * 32 + g * 8);
  asm volatile("s_waitcnt vmcnt(0)" ::: "memory");

  int koff[2], voff[2];
#pragma unroll
  for (int i = 0; i < 2; ++i) {
    int c = (i * 8 + wave) * 64 + lane;        // 0..1023
    int kr = c >> 4, kj = c & 15;
    koff[i] = kr * 4096 + (kj ^ (kr & 7)) * 8;
    int vr = c >> 3, vj = c & 7;
    voff[i] = vr * 4096 + (vj ^ (vr & 7)) * 8;
  }
  const int sw = r15 & 7;

  f32x4 oacc[8] = {};
  float m = -1e30f, l = 0.f;

  // prologue: stage tile 0
#pragma unroll
  for (int i = 0; i < 2; ++i) {
    gload_lds16(Kp + koff[i], (char*)Ks[0] + (i * 8 + wave) * 1024);
    gload_lds16(Vp + voff[i], (char*)Vs[0] + (i * 8 + wave) * 1024);
  }

  for (int t = 0; t < 32; ++t) {
    const int cur = t & 1;
    if (t < 31) {
      const size_t kv0n = (size_t)(t + 1) * 64;
#pragma unroll
      for (int i = 0; i < 2; ++i) {
        gload_lds16(Kp + kv0n * 4096 + koff[i], (char*)Ks[cur ^ 1] + (i * 8 + wave) * 1024);
        gload_lds16(Vp + kv0n + voff[i], (char*)Vs[cur ^ 1] + (i * 8 + wave) * 1024);
      }
      asm volatile("s_waitcnt vmcnt(4)" ::: "memory");  // drain tile t, keep t+1 in flight
    } else {
      asm volatile("s_waitcnt vmcnt(0)" ::: "memory");
    }
    __builtin_amdgcn_s_barrier();
    __builtin_amdgcn_sched_barrier(0);

    f32x4 sacc[4] = {};
    __builtin_amdgcn_s_setprio(1);
#pragma unroll
    for (int tt = 0; tt < 4; ++tt) {
      const int krow = tt * 16 + r15;
#pragma unroll
      for (int kc = 0; kc < 4; ++kc) {
        bf16x8 kf = *(const bf16x8*)((const char*)Ks[cur] + krow * 256 +
                                     (((kc * 4 + g) ^ sw) << 4));
        sacc[tt] = __builtin_amdgcn_mfma_f32_16x16x32_bf16(kf, qf[kc], sacc[tt], 0, 0, 0);
      }
    }
    __builtin_amdgcn_s_setprio(0);

    float mx = fmaxf(fmaxf(sacc[0][0], sacc[0][1]), fmaxf(sacc[0][2], sacc[0][3]));
#pragma unroll
    for (int tt = 1; tt < 4; ++tt)
#pragma unroll
      for (int r = 0; r < 4; ++r) mx = fmaxf(mx, sacc[tt][r]);
    mx = fmaxf(mx, __shfl_xor(mx, 16));
    mx = fmaxf(mx, __shfl_xor(mx, 32));

    if (!__all(mx - m <= 8.0f)) {              // defer-max
      float mn = fmaxf(m, mx);
      float alpha = __builtin_amdgcn_exp2f(m - mn);
#pragma unroll
      for (int dt = 0; dt < 8; ++dt) oacc[dt] *= alpha;
      l *= alpha;
      m = mn;
    }

    float rs = 0.f;
    u32 pk[4][2];     // pk[tt][w] = bf16pair(kv = 16tt + 4g + 2w, +1)
#pragma unroll
    for (int tt = 0; tt < 4; ++tt)
#pragma unroll
      for (int w = 0; w < 2; ++w) {
        float p0 = __builtin_amdgcn_exp2f(sacc[tt][2 * w] - m);
        float p1 = __builtin_amdgcn_exp2f(sacc[tt][2 * w + 1] - m);
        rs += p0 + p1;
        pk[tt][w] = cvtpk_bf16(p0, p1);
      }
    rs += __shfl_xor(rs, 16);
    rs += __shfl_xor(rs, 32);
    l += rs;

    // O^T += V^T · P^T (zero-shuffle B; A uses the same k-slot placement)
    __builtin_amdgcn_s_setprio(1);
#pragma unroll
    for (int dt = 0; dt < 8; ++dt) {
      const int d = dt * 16 + r15;
      const char* vrow = (const char*)Vs[cur] + d * 128 + 8 * (g & 1);
      const int vsw = d & 7;
#pragma unroll
      for (int kh = 0; kh < 2; ++kh) {
        union { u32 u4[4]; bf16x8 v; } af, bfv;
        *(u32x2*)&af.u4[0] = *(const u32x2*)(vrow + (((kh * 4 + (g >> 1)) ^ vsw) << 4));
        *(u32x2*)&af.u4[2] = *(const u32x2*)(vrow + (((kh * 4 + 2 + (g >> 1)) ^ vsw) << 4));
        bfv.u4[0] = pk[2 * kh][0];
        bfv.u4[1] = pk[2 * kh][1];
        bfv.u4[2] = pk[2 * kh + 1][0];
        bfv.u4[3] = pk[2 * kh + 1][1];
        oacc[dt] = __builtin_amdgcn_mfma_f32_16x16x32_bf16(af.v, bfv.v, oacc[dt], 0, 0, 0);
      }
    }
    __builtin_amdgcn_s_setprio(0);

    __builtin_amdgcn_s_barrier();              // all waves done with buf[cur]
  }

  const float inv = 1.0f / l;
  u16* Ob = O + ((size_t)(b * 2048 + qrow)) * 2048 + h * 128;
#pragma unroll
  for (int dt = 0; dt < 8; ++dt) {
    u32x2 pair;
    pair[0] = cvtpk_bf16(oacc[dt][0] * inv, oacc[dt][1] * inv);
    pair[1] = cvtpk_bf16(oacc[dt][2] * inv, oacc[dt][3] * inv);
    *(u32x2*)(Ob + dt * 16 + 4 * g) = pair;
  }
}

// ---------------- host ----------------
extern "C" void kernel_launch(void* const* d_in, const int* in_sizes, int n_in,
                              void* d_out, int out_size, void* d_ws, size_t ws_size,
                              hipStream_t stream) {
  const float* x  = (const float*)d_in[0];
  const float* Wq = (const float*)d_in[1];
  const float* Wk = (const float*)d_in[2];
  const float* Wv = (const float*)d_in[3];
  const float* Wo = (const float*)d_in[4];
  const float* bo = (const float*)d_in[5];
  float* out = (float*)d_out;

  char* ws = (char*)d_ws;
  u16* xb    = (u16*)ws;                               // 16 MiB (reused as attn O)
  u16* WqkvT = (u16*)(ws + (size_t)16 * 1024 * 1024);  // 24 MiB [6144][2048]
  u16* WoT   = (u16*)(ws + (size_t)40 * 1024 * 1024);  // 8 MiB  [2048][2048]
  u16* QK    = (u16*)(ws + (size_t)48 * 1024 * 1024);  // 32 MiB [4096][4096]
  u16* VtG   = (u16*)(ws + (size_t)80 * 1024 * 1024);  // 16 MiB [2048][4096]
  u16* Oattn = xb;

  const float C2 = 0.12753102f;   // (1/sqrt(128)) * log2(e), folded into Wk

  cast_x_kernel<<<4096, 256, 0, stream>>>(x, xb);

  TC4 p;
  p.W[0] = Wq; p.W[1] = Wk; p.W[2] = Wv; p.W[3] = Wo;
  p.D[0] = WqkvT;
  p.D[1] = WqkvT + (size_t)2048 * 2048;
  p.D[2] = WqkvT + (size_t)4096 * 2048;
  p.D[3] = WoT;
  p.s[0] = 1.0f; p.s[1] = C2; p.s[2] = 1.0f; p.s[3] = 1.0f;
  transcast4<<<dim3(64, 64, 4), dim3(32, 8), 0, stream>>>(p);

  // QK = xb @ [Wq|Wk_scaled]   (M=4096, N=4096, K=2048), 256x256 tiles, 256 wgs
  gemm256<0, 256, 256, 2, 4><<<dim3(16, 16), 512, 0, stream>>>(
      xb, WqkvT, nullptr, QK, nullptr, 4096, 4096, 2048, 2048, 2048, 4096);
  // V^T = Wv^T @ x^T    (M=2048, N=4096, K=2048), 128x256 tiles, 256 wgs
  gemm256<0, 128, 256, 2, 4><<<dim3(16, 16), 512, 0, stream>>>(
      WqkvT + (size_t)4096 * 2048, xb, nullptr, VtG, nullptr,
      2048, 4096, 2048, 2048, 2048, 4096);
  // attention: 128 q-rows per block, 512 blocks of 512 threads
  attn_kernel<<<dim3(16, 16, 2), 512, 0, stream>>>(QK, VtG, Oattn);
  // out = O @ Wo + bo   (M=4096, N=2048, K=2048), 256x128 tiles, 256 wgs
  gemm256<1, 256, 128, 4, 2><<<dim3(16, 16), 512, 0, stream>>>(
      Oattn, WoT, out, nullptr, bo, 4096, 2048, 2048, 2048, 2048, 2048);
}

// Round 17
// 271.367 us; speedup vs baseline: 1.0610x; 1.0610x over previous
//
#include <hip/hip_runtime.h>
#include <hip/hip_bf16.h>

typedef unsigned short u16;
typedef unsigned int   u32;
typedef __bf16 bf16x8 __attribute__((ext_vector_type(8)));
typedef float  f32x4  __attribute__((ext_vector_type(4)));
typedef u16    u16x8  __attribute__((ext_vector_type(8)));
typedef u32    u32x2  __attribute__((ext_vector_type(2)));

#define GAS __attribute__((address_space(1)))
#define LAS __attribute__((address_space(3)))

__device__ __forceinline__ void gload_lds16(const void* g, void* lds) {
  __builtin_amdgcn_global_load_lds((GAS u32*)g, (LAS u32*)lds, 16, 0, 0);
}

__device__ __forceinline__ u16 f2bf(float f) {
  union { float f; u32 u; } v; v.f = f;
  u32 r = v.u + 0x7FFFu + ((v.u >> 16) & 1u);   // round-to-nearest-even
  return (u16)(r >> 16);
}

__device__ __forceinline__ u32 cvtpk_bf16(float lo, float hi) {
  u32 r;
  asm("v_cvt_pk_bf16_f32 %0, %1, %2" : "=v"(r) : "v"(lo), "v"(hi));
  return r;
}

template <int N> __device__ __forceinline__ void wait_vmcnt() {
  if constexpr (N == 3)      asm volatile("s_waitcnt vmcnt(3)" ::: "memory");
  else if constexpr (N == 4) asm volatile("s_waitcnt vmcnt(4)" ::: "memory");
  else                       asm volatile("s_waitcnt vmcnt(0)" ::: "memory");
}

// ---------------- elementwise cast x: f32 -> bf16 (8 elems/thread) ----------------
__global__ __launch_bounds__(256) void cast_x_kernel(const float* __restrict__ x,
                                                     u16* __restrict__ xb) {
  int i = (blockIdx.x * 256 + threadIdx.x) * 8;
  float4 a = *(const float4*)(x + i);
  float4 b = *(const float4*)(x + i + 4);
  u16x8 o;
  o[0] = f2bf(a.x); o[1] = f2bf(a.y); o[2] = f2bf(a.z); o[3] = f2bf(a.w);
  o[4] = f2bf(b.x); o[5] = f2bf(b.y); o[6] = f2bf(b.z); o[7] = f2bf(b.w);
  *(u16x8*)(xb + i) = o;
}

// ------------- fused transpose-cast: 4x W[k][n] f32 -> WT[n][k] bf16 (x scale) ----
struct TC4 {
  const float* W[4];
  u16* D[4];
  float s[4];
};
__global__ __launch_bounds__(256) void transcast4(TC4 p) {
  __shared__ float t[32][33];
  const int tx = threadIdx.x, ty = threadIdx.y;      // 32 x 8
  const int z = blockIdx.z;
  const float* __restrict__ W = p.W[z];
  u16* __restrict__ WT = p.D[z];
  const float scale = p.s[z];
  const int c0 = blockIdx.x * 32, r0 = blockIdx.y * 32;
#pragma unroll
  for (int i = 0; i < 4; ++i)
    t[ty + i * 8][tx] = W[(r0 + ty + i * 8) * 2048 + c0 + tx];
  __syncthreads();
#pragma unroll
  for (int i = 0; i < 4; ++i)
    WT[(c0 + ty + i * 8) * 2048 + r0 + tx] = f2bf(t[tx][ty + i * 8] * scale);
}

// ---------------- GEMM BMxBN, BK=64, 8 waves, 4-phase counted-vmcnt pipeline ------
// (exact R16 state — passed; unchanged this round)
template <int OUTF32, int BM, int BN, int WM, int WN>
__global__ __launch_bounds__(512, 2) void gemm256(
    const u16* __restrict__ A, const u16* __restrict__ B,
    float* __restrict__ Cf, u16* __restrict__ Cb, const float* __restrict__ bias,
    int M, int N, int K, int lda, int ldb, int ldc) {
  constexpr int PM = BM / WM, PN = BN / WN;    // per-wave output
  constexpr int MI = PM / 16, NI = PN / 16;    // acc tile counts
  constexpr int CA = BM / 128, CB = BN / 128;  // staging chunks per thread
  __shared__ alignas(16) u16 lds[2][2][(BM + BN) * 32];

  const int tid = threadIdx.x;                 // 0..511
  const int lane = tid & 63, wave = tid >> 6;
  const int wm = wave / WN, wn = wave % WN;
  const int r15 = lane & 15, g = lane >> 4;

  const int gx = gridDim.x;
  const int nwg = gx * gridDim.y;
  const int orig = blockIdx.y * gx + blockIdx.x;
  const int wg = (orig & 7) * (nwg >> 3) + (orig >> 3);
  const int tm = (wg % gx) * BM, tn = (wg / gx) * BN;

  int aoff[CA], boff[CB];
#pragma unroll
  for (int i = 0; i < CA; ++i) {
    int c = i * 512 + tid, row = c >> 2, ch = c & 3;
    aoff[i] = (tm + row) * lda + (ch ^ ((row >> 1) & 3)) * 8;
  }
#pragma unroll
  for (int i = 0; i < CB; ++i) {
    int c = i * 512 + tid, row = c >> 2, ch = c & 3;
    boff[i] = (tn + row) * ldb + (ch ^ ((row >> 1) & 3)) * 8;
  }

  auto stageA = [&](int kofs, int buf, int ks) {
#pragma unroll
    for (int i = 0; i < CA; ++i)
      gload_lds16(A + aoff[i] + kofs,
                  (char*)&lds[buf][ks][0] + (i * 8 + wave) * 1024);
  };
  auto stageB = [&](int kofs, int buf, int ks) {
#pragma unroll
    for (int i = 0; i < CB; ++i)
      gload_lds16(B + boff[i] + kofs,
                  (char*)&lds[buf][ks][BM * 32] + (i * 8 + wave) * 1024);
  };

  f32x4 acc[MI][NI] = {};
  const int NT = K / 64;
  const int fsw = (r15 >> 1) & 3;              // fragment-read chunk swizzle

  stageA(0, 0, 0);  stageB(0, 0, 0);
  stageA(32, 0, 1); stageB(32, 0, 1);

  for (int t = 0; t < NT; ++t) {
    const int cur = t & 1, nxt = cur ^ 1;
    const int kn = (t + 1 < NT) ? (t + 1) * 64 : 0;   // last tile: dummy restage
#pragma unroll
    for (int ks = 0; ks < 2; ++ks) {
      // ---- phase 1: publish this ks-group, low-half MFMA ----
      wait_vmcnt<CA + CB>();                   // drain this group's operands only
      __builtin_amdgcn_s_barrier();
      __builtin_amdgcn_sched_barrier(0);

      const char* Ab = (const char*)&lds[cur][ks][0];
      const char* Bb = (const char*)&lds[cur][ks][BM * 32];
      bf16x8 bfr[NI], af[MI / 2];
#pragma unroll
      for (int ni = 0; ni < NI; ++ni)
        bfr[ni] = *(const bf16x8*)(Bb + (wn * PN + ni * 16 + r15) * 64 +
                                   ((g ^ fsw) << 4));
#pragma unroll
      for (int mi = 0; mi < MI / 2; ++mi)
        af[mi] = *(const bf16x8*)(Ab + (wm * PM + mi * 16 + r15) * 64 +
                                  ((g ^ fsw) << 4));

      stageA(kn + ks * 32, nxt, ks);

      __builtin_amdgcn_s_setprio(1);
#pragma unroll
      for (int mi = 0; mi < MI / 2; ++mi)
#pragma unroll
        for (int ni = 0; ni < NI; ++ni)
          acc[mi][ni] = __builtin_amdgcn_mfma_f32_16x16x32_bf16(af[mi], bfr[ni],
                                                                acc[mi][ni], 0, 0, 0);
      __builtin_amdgcn_s_setprio(0);

      // ---- phase 2: high-half MFMA ----
      __builtin_amdgcn_s_barrier();
      __builtin_amdgcn_sched_barrier(0);

#pragma unroll
      for (int mi = 0; mi < MI / 2; ++mi)
        af[mi] = *(const bf16x8*)(Ab + (wm * PM + (mi + MI / 2) * 16 + r15) * 64 +
                                  ((g ^ fsw) << 4));

      stageB(kn + ks * 32, nxt, ks);

      __builtin_amdgcn_s_setprio(1);
#pragma unroll
      for (int mi = 0; mi < MI / 2; ++mi)
#pragma unroll
        for (int ni = 0; ni < NI; ++ni)
          acc[mi + MI / 2][ni] = __builtin_amdgcn_mfma_f32_16x16x32_bf16(
              af[mi], bfr[ni], acc[mi + MI / 2][ni], 0, 0, 0);
      __builtin_amdgcn_s_setprio(0);
    }
  }

  // epilogue
#pragma unroll
  for (int mi = 0; mi < MI; ++mi)
#pragma unroll
    for (int ni = 0; ni < NI; ++ni)
#pragma unroll
      for (int r = 0; r < 4; ++r) {
        int m = tm + wm * PM + mi * 16 + g * 4 + r;
        int n = tn + wn * PN + ni * 16 + r15;
        float v = acc[mi][ni][r];
        if (OUTF32) Cf[(size_t)m * ldc + n] = v + bias[n];
        else        Cb[(size_t)m * ldc + n] = f2bf(v);
      }
}

// ---------------- flash attention: 8 waves x 2 q-strips, KVBLK=64 -----------------
// QK:  [B*S][4096] bf16 rows = {Q[h][d], K_scaled[h][d]}  (K pre-scaled by C2)
// VtG: [2048][4096] bf16 = V^T, row (h*128+d), col (b*2048+s)
// O:   [B*S][2048] bf16
// QBLK=256: wave owns 2 q-strips of 16. K fragment (kf) and V fragment (af) are
// read from LDS ONCE and feed TWO MFMAs (one per strip) -> per-CU LDS traffic
// halves (attn was LDS-pipe-bound: ~120us of LDS reads vs 126us runtime).
// Staging, barriers, vmcnt ledger, softmax math, PV placement: byte-identical to
// the 4x-proven R8 structure; softmax/epilogue duplicated per strip.
__global__ __launch_bounds__(512, 2) void attn_kernel(const u16* __restrict__ QK,
                                                      const u16* __restrict__ VtG,
                                                      u16* __restrict__ O) {
  __shared__ alignas(16) u16 Ks[2][64 * 128];   // 16KB each
  __shared__ alignas(16) u16 Vs[2][128 * 64];   // 16KB each

  const int tid = threadIdx.x, lane = tid & 63, wave = tid >> 6;
  const int r15 = lane & 15, g = lane >> 4;

  // 256 wgs: bijective XCD swizzle
  const int orig = (blockIdx.z * 16 + blockIdx.y) * 8 + blockIdx.x;
  const int wg = (orig & 7) * 32 + (orig >> 3);
  const int qb = wg & 7, h = (wg >> 3) & 15, b = wg >> 7;

  const u16* Qp = QK + (size_t)b * 2048 * 4096 + h * 128;
  const u16* Kp = Qp + 2048;
  const u16* Vp = VtG + (size_t)(h * 128) * 4096 + b * 2048;

  // Q fragments for both strips; strip s rows: qb*256 + wave*32 + s*16 + r15
  const int qrow0 = qb * 256 + wave * 32 + r15;
  bf16x8 qf[2][4];
#pragma unroll
  for (int s = 0; s < 2; ++s)
#pragma unroll
    for (int kc = 0; kc < 4; ++kc)
      qf[s][kc] = *(const bf16x8*)(Qp + (size_t)(qrow0 + s * 16) * 4096 +
                                   kc * 32 + g * 8);
  asm volatile("s_waitcnt vmcnt(0)" ::: "memory");

  int koff[2], voff[2];
#pragma unroll
  for (int i = 0; i < 2; ++i) {
    int c = (i * 8 + wave) * 64 + lane;        // 0..1023
    int kr = c >> 4, kj = c & 15;
    koff[i] = kr * 4096 + (kj ^ (kr & 7)) * 8;
    int vr = c >> 3, vj = c & 7;
    voff[i] = vr * 4096 + (vj ^ (vr & 7)) * 8;
  }
  const int sw = r15 & 7;

  f32x4 oacc[2][8] = {};
  float m[2] = {-1e30f, -1e30f}, l[2] = {0.f, 0.f};

  // prologue: stage tile 0
#pragma unroll
  for (int i = 0; i < 2; ++i) {
    gload_lds16(Kp + koff[i], (char*)Ks[0] + (i * 8 + wave) * 1024);
    gload_lds16(Vp + voff[i], (char*)Vs[0] + (i * 8 + wave) * 1024);
  }

  for (int t = 0; t < 32; ++t) {
    const int cur = t & 1;
    if (t < 31) {
      const size_t kv0n = (size_t)(t + 1) * 64;
#pragma unroll
      for (int i = 0; i < 2; ++i) {
        gload_lds16(Kp + kv0n * 4096 + koff[i], (char*)Ks[cur ^ 1] + (i * 8 + wave) * 1024);
        gload_lds16(Vp + kv0n + voff[i], (char*)Vs[cur ^ 1] + (i * 8 + wave) * 1024);
      }
      asm volatile("s_waitcnt vmcnt(4)" ::: "memory");  // drain tile t, keep t+1 in flight
    } else {
      asm volatile("s_waitcnt vmcnt(0)" ::: "memory");
    }
    __builtin_amdgcn_s_barrier();
    __builtin_amdgcn_sched_barrier(0);

    // S^T = K_scaled · Q^T for BOTH strips; kf read once, used twice
    f32x4 sacc[2][4] = {};
    __builtin_amdgcn_s_setprio(1);
#pragma unroll
    for (int tt = 0; tt < 4; ++tt) {
      const int krow = tt * 16 + r15;
#pragma unroll
      for (int kc = 0; kc < 4; ++kc) {
        bf16x8 kf = *(const bf16x8*)((const char*)Ks[cur] + krow * 256 +
                                     (((kc * 4 + g) ^ sw) << 4));
        sacc[0][tt] = __builtin_amdgcn_mfma_f32_16x16x32_bf16(kf, qf[0][kc], sacc[0][tt], 0, 0, 0);
        sacc[1][tt] = __builtin_amdgcn_mfma_f32_16x16x32_bf16(kf, qf[1][kc], sacc[1][tt], 0, 0, 0);
      }
    }
    __builtin_amdgcn_s_setprio(0);

    // online softmax per strip (exact proven sequence, strip-indexed)
    u32 pk[2][4][2];
#pragma unroll
    for (int s = 0; s < 2; ++s) {
      float mx = fmaxf(fmaxf(sacc[s][0][0], sacc[s][0][1]),
                       fmaxf(sacc[s][0][2], sacc[s][0][3]));
#pragma unroll
      for (int tt = 1; tt < 4; ++tt)
#pragma unroll
        for (int r = 0; r < 4; ++r) mx = fmaxf(mx, sacc[s][tt][r]);
      mx = fmaxf(mx, __shfl_xor(mx, 16));
      mx = fmaxf(mx, __shfl_xor(mx, 32));

      if (!__all(mx - m[s] <= 8.0f)) {         // defer-max
        float mn = fmaxf(m[s], mx);
        float alpha = __builtin_amdgcn_exp2f(m[s] - mn);
#pragma unroll
        for (int dt = 0; dt < 8; ++dt) oacc[s][dt] *= alpha;
        l[s] *= alpha;
        m[s] = mn;
      }

      float rs = 0.f;
#pragma unroll
      for (int tt = 0; tt < 4; ++tt)
#pragma unroll
        for (int w = 0; w < 2; ++w) {
          float p0 = __builtin_amdgcn_exp2f(sacc[s][tt][2 * w] - m[s]);
          float p1 = __builtin_amdgcn_exp2f(sacc[s][tt][2 * w + 1] - m[s]);
          rs += p0 + p1;
          pk[s][tt][w] = cvtpk_bf16(p0, p1);
        }
      rs += __shfl_xor(rs, 16);
      rs += __shfl_xor(rs, 32);
      l[s] += rs;
    }

    // O^T += V^T · P^T for BOTH strips; af read once, used twice
    __builtin_amdgcn_s_setprio(1);
#pragma unroll
    for (int dt = 0; dt < 8; ++dt) {
      const int d = dt * 16 + r15;
      const char* vrow = (const char*)Vs[cur] + d * 128 + 8 * (g & 1);
      const int vsw = d & 7;
#pragma unroll
      for (int kh = 0; kh < 2; ++kh) {
        union { u32 u4[4]; bf16x8 v; } af, b0, b1;
        *(u32x2*)&af.u4[0] = *(const u32x2*)(vrow + (((kh * 4 + (g >> 1)) ^ vsw) << 4));
        *(u32x2*)&af.u4[2] = *(const u32x2*)(vrow + (((kh * 4 + 2 + (g >> 1)) ^ vsw) << 4));
        b0.u4[0] = pk[0][2 * kh][0];     b0.u4[1] = pk[0][2 * kh][1];
        b0.u4[2] = pk[0][2 * kh + 1][0]; b0.u4[3] = pk[0][2 * kh + 1][1];
        b1.u4[0] = pk[1][2 * kh][0];     b1.u4[1] = pk[1][2 * kh][1];
        b1.u4[2] = pk[1][2 * kh + 1][0]; b1.u4[3] = pk[1][2 * kh + 1][1];
        oacc[0][dt] = __builtin_amdgcn_mfma_f32_16x16x32_bf16(af.v, b0.v, oacc[0][dt], 0, 0, 0);
        oacc[1][dt] = __builtin_amdgcn_mfma_f32_16x16x32_bf16(af.v, b1.v, oacc[1][dt], 0, 0, 0);
      }
    }
    __builtin_amdgcn_s_setprio(0);

    __builtin_amdgcn_s_barrier();              // all waves done with buf[cur]
  }

  // epilogue per strip
#pragma unroll
  for (int s = 0; s < 2; ++s) {
    const float inv = 1.0f / l[s];
    u16* Ob = O + ((size_t)(b * 2048 + qrow0 + s * 16)) * 2048 + h * 128;
#pragma unroll
    for (int dt = 0; dt < 8; ++dt) {
      u32x2 pair;
      pair[0] = cvtpk_bf16(oacc[s][dt][0] * inv, oacc[s][dt][1] * inv);
      pair[1] = cvtpk_bf16(oacc[s][dt][2] * inv, oacc[s][dt][3] * inv);
      *(u32x2*)(Ob + dt * 16 + 4 * g) = pair;
    }
  }
}

// ---------------- host ----------------
extern "C" void kernel_launch(void* const* d_in, const int* in_sizes, int n_in,
                              void* d_out, int out_size, void* d_ws, size_t ws_size,
                              hipStream_t stream) {
  const float* x  = (const float*)d_in[0];
  const float* Wq = (const float*)d_in[1];
  const float* Wk = (const float*)d_in[2];
  const float* Wv = (const float*)d_in[3];
  const float* Wo = (const float*)d_in[4];
  const float* bo = (const float*)d_in[5];
  float* out = (float*)d_out;

  char* ws = (char*)d_ws;
  u16* xb    = (u16*)ws;                               // 16 MiB (reused as attn O)
  u16* WqkvT = (u16*)(ws + (size_t)16 * 1024 * 1024);  // 24 MiB [6144][2048]
  u16* WoT   = (u16*)(ws + (size_t)40 * 1024 * 1024);  // 8 MiB  [2048][2048]
  u16* QK    = (u16*)(ws + (size_t)48 * 1024 * 1024);  // 32 MiB [4096][4096]
  u16* VtG   = (u16*)(ws + (size_t)80 * 1024 * 1024);  // 16 MiB [2048][4096]
  u16* Oattn = xb;

  const float C2 = 0.12753102f;   // (1/sqrt(128)) * log2(e), folded into Wk

  cast_x_kernel<<<4096, 256, 0, stream>>>(x, xb);

  TC4 p;
  p.W[0] = Wq; p.W[1] = Wk; p.W[2] = Wv; p.W[3] = Wo;
  p.D[0] = WqkvT;
  p.D[1] = WqkvT + (size_t)2048 * 2048;
  p.D[2] = WqkvT + (size_t)4096 * 2048;
  p.D[3] = WoT;
  p.s[0] = 1.0f; p.s[1] = C2; p.s[2] = 1.0f; p.s[3] = 1.0f;
  transcast4<<<dim3(64, 64, 4), dim3(32, 8), 0, stream>>>(p);

  // QK = xb @ [Wq|Wk_scaled]   (M=4096, N=4096, K=2048), 256x256 tiles, 256 wgs
  gemm256<0, 256, 256, 2, 4><<<dim3(16, 16), 512, 0, stream>>>(
      xb, WqkvT, nullptr, QK, nullptr, 4096, 4096, 2048, 2048, 2048, 4096);
  // V^T = Wv^T @ x^T    (M=2048, N=4096, K=2048), 128x256 tiles, 256 wgs
  gemm256<0, 128, 256, 2, 4><<<dim3(16, 16), 512, 0, stream>>>(
      WqkvT + (size_t)4096 * 2048, xb, nullptr, VtG, nullptr,
      2048, 4096, 2048, 2048, 2048, 4096);
  // attention: 256 q-rows per block, 256 blocks of 512 threads (2 strips/wave)
  attn_kernel<<<dim3(8, 16, 2), 512, 0, stream>>>(QK, VtG, Oattn);
  // out = O @ Wo + bo   (M=4096, N=2048, K=2048), 256x128 tiles, 256 wgs
  gemm256<1, 256, 128, 4, 2><<<dim3(16, 16), 512, 0, stream>>>(
      Oattn, WoT, out, nullptr, bo, 4096, 2048, 2048, 2048, 2048, 2048);
}

// Round 18
// 264.366 us; speedup vs baseline: 1.0891x; 1.0265x over previous
//
#include <hip/hip_runtime.h>
#include <hip/hip_bf16.h>

typedef unsigned short u16;
typedef unsigned int   u32;
typedef __bf16 bf16x8 __attribute__((ext_vector_type(8)));
typedef float  f32x4  __attribute__((ext_vector_type(4)));
typedef u16    u16x8  __attribute__((ext_vector_type(8)));
typedef u32    u32x2  __attribute__((ext_vector_type(2)));

#define GAS __attribute__((address_space(1)))
#define LAS __attribute__((address_space(3)))

__device__ __forceinline__ void gload_lds16(const void* g, void* lds) {
  __builtin_amdgcn_global_load_lds((GAS u32*)g, (LAS u32*)lds, 16, 0, 0);
}

__device__ __forceinline__ u16 f2bf(float f) {
  union { float f; u32 u; } v; v.f = f;
  u32 r = v.u + 0x7FFFu + ((v.u >> 16) & 1u);   // round-to-nearest-even
  return (u16)(r >> 16);
}

__device__ __forceinline__ u32 cvtpk_bf16(float lo, float hi) {
  u32 r;
  asm("v_cvt_pk_bf16_f32 %0, %1, %2" : "=v"(r) : "v"(lo), "v"(hi));
  return r;
}

template <int N> __device__ __forceinline__ void wait_vmcnt() {
  if constexpr (N == 3)      asm volatile("s_waitcnt vmcnt(3)" ::: "memory");
  else if constexpr (N == 4) asm volatile("s_waitcnt vmcnt(4)" ::: "memory");
  else if constexpr (N == 8) asm volatile("s_waitcnt vmcnt(8)" ::: "memory");
  else                       asm volatile("s_waitcnt vmcnt(0)" ::: "memory");
}

// ---------------- elementwise cast x: f32 -> bf16 (8 elems/thread) ----------------
__global__ __launch_bounds__(256) void cast_x_kernel(const float* __restrict__ x,
                                                     u16* __restrict__ xb) {
  int i = (blockIdx.x * 256 + threadIdx.x) * 8;
  float4 a = *(const float4*)(x + i);
  float4 b = *(const float4*)(x + i + 4);
  u16x8 o;
  o[0] = f2bf(a.x); o[1] = f2bf(a.y); o[2] = f2bf(a.z); o[3] = f2bf(a.w);
  o[4] = f2bf(b.x); o[5] = f2bf(b.y); o[6] = f2bf(b.z); o[7] = f2bf(b.w);
  *(u16x8*)(xb + i) = o;
}

// ------------- fused transpose-cast: 4x W[k][n] f32 -> WT[n][k] bf16 (x scale) ----
struct TC4 {
  const float* W[4];
  u16* D[4];
  float s[4];
};
__global__ __launch_bounds__(256) void transcast4(TC4 p) {
  __shared__ float t[32][33];
  const int tx = threadIdx.x, ty = threadIdx.y;      // 32 x 8
  const int z = blockIdx.z;
  const float* __restrict__ W = p.W[z];
  u16* __restrict__ WT = p.D[z];
  const float scale = p.s[z];
  const int c0 = blockIdx.x * 32, r0 = blockIdx.y * 32;
#pragma unroll
  for (int i = 0; i < 4; ++i)
    t[ty + i * 8][tx] = W[(r0 + ty + i * 8) * 2048 + c0 + tx];
  __syncthreads();
#pragma unroll
  for (int i = 0; i < 4; ++i)
    WT[(c0 + ty + i * 8) * 2048 + r0 + tx] = f2bf(t[tx][ty + i * 8] * scale);
}

// ---------------- GEMM BMxBN, BK=64, 8 waves, 4-phase counted-vmcnt pipeline ------
// (exact R16 state — passed twice; unchanged this round)
template <int OUTF32, int BM, int BN, int WM, int WN>
__global__ __launch_bounds__(512, 2) void gemm256(
    const u16* __restrict__ A, const u16* __restrict__ B,
    float* __restrict__ Cf, u16* __restrict__ Cb, const float* __restrict__ bias,
    int M, int N, int K, int lda, int ldb, int ldc) {
  constexpr int PM = BM / WM, PN = BN / WN;    // per-wave output
  constexpr int MI = PM / 16, NI = PN / 16;    // acc tile counts
  constexpr int CA = BM / 128, CB = BN / 128;  // staging chunks per thread
  __shared__ alignas(16) u16 lds[2][2][(BM + BN) * 32];

  const int tid = threadIdx.x;                 // 0..511
  const int lane = tid & 63, wave = tid >> 6;
  const int wm = wave / WN, wn = wave % WN;
  const int r15 = lane & 15, g = lane >> 4;

  const int gx = gridDim.x;
  const int nwg = gx * gridDim.y;
  const int orig = blockIdx.y * gx + blockIdx.x;
  const int wg = (orig & 7) * (nwg >> 3) + (orig >> 3);
  const int tm = (wg % gx) * BM, tn = (wg / gx) * BN;

  int aoff[CA], boff[CB];
#pragma unroll
  for (int i = 0; i < CA; ++i) {
    int c = i * 512 + tid, row = c >> 2, ch = c & 3;
    aoff[i] = (tm + row) * lda + (ch ^ ((row >> 1) & 3)) * 8;
  }
#pragma unroll
  for (int i = 0; i < CB; ++i) {
    int c = i * 512 + tid, row = c >> 2, ch = c & 3;
    boff[i] = (tn + row) * ldb + (ch ^ ((row >> 1) & 3)) * 8;
  }

  auto stageA = [&](int kofs, int buf, int ks) {
#pragma unroll
    for (int i = 0; i < CA; ++i)
      gload_lds16(A + aoff[i] + kofs,
                  (char*)&lds[buf][ks][0] + (i * 8 + wave) * 1024);
  };
  auto stageB = [&](int kofs, int buf, int ks) {
#pragma unroll
    for (int i = 0; i < CB; ++i)
      gload_lds16(B + boff[i] + kofs,
                  (char*)&lds[buf][ks][BM * 32] + (i * 8 + wave) * 1024);
  };

  f32x4 acc[MI][NI] = {};
  const int NT = K / 64;
  const int fsw = (r15 >> 1) & 3;              // fragment-read chunk swizzle

  stageA(0, 0, 0);  stageB(0, 0, 0);
  stageA(32, 0, 1); stageB(32, 0, 1);

  for (int t = 0; t < NT; ++t) {
    const int cur = t & 1, nxt = cur ^ 1;
    const int kn = (t + 1 < NT) ? (t + 1) * 64 : 0;   // last tile: dummy restage
#pragma unroll
    for (int ks = 0; ks < 2; ++ks) {
      // ---- phase 1: publish this ks-group, low-half MFMA ----
      wait_vmcnt<CA + CB>();                   // drain this group's operands only
      __builtin_amdgcn_s_barrier();
      __builtin_amdgcn_sched_barrier(0);

      const char* Ab = (const char*)&lds[cur][ks][0];
      const char* Bb = (const char*)&lds[cur][ks][BM * 32];
      bf16x8 bfr[NI], af[MI / 2];
#pragma unroll
      for (int ni = 0; ni < NI; ++ni)
        bfr[ni] = *(const bf16x8*)(Bb + (wn * PN + ni * 16 + r15) * 64 +
                                   ((g ^ fsw) << 4));
#pragma unroll
      for (int mi = 0; mi < MI / 2; ++mi)
        af[mi] = *(const bf16x8*)(Ab + (wm * PM + mi * 16 + r15) * 64 +
                                  ((g ^ fsw) << 4));

      stageA(kn + ks * 32, nxt, ks);

      __builtin_amdgcn_s_setprio(1);
#pragma unroll
      for (int mi = 0; mi < MI / 2; ++mi)
#pragma unroll
        for (int ni = 0; ni < NI; ++ni)
          acc[mi][ni] = __builtin_amdgcn_mfma_f32_16x16x32_bf16(af[mi], bfr[ni],
                                                                acc[mi][ni], 0, 0, 0);
      __builtin_amdgcn_s_setprio(0);

      // ---- phase 2: high-half MFMA ----
      __builtin_amdgcn_s_barrier();
      __builtin_amdgcn_sched_barrier(0);

#pragma unroll
      for (int mi = 0; mi < MI / 2; ++mi)
        af[mi] = *(const bf16x8*)(Ab + (wm * PM + (mi + MI / 2) * 16 + r15) * 64 +
                                  ((g ^ fsw) << 4));

      stageB(kn + ks * 32, nxt, ks);

      __builtin_amdgcn_s_setprio(1);
#pragma unroll
      for (int mi = 0; mi < MI / 2; ++mi)
#pragma unroll
        for (int ni = 0; ni < NI; ++ni)
          acc[mi + MI / 2][ni] = __builtin_amdgcn_mfma_f32_16x16x32_bf16(
              af[mi], bfr[ni], acc[mi + MI / 2][ni], 0, 0, 0);
      __builtin_amdgcn_s_setprio(0);
    }
  }

  // epilogue
#pragma unroll
  for (int mi = 0; mi < MI; ++mi)
#pragma unroll
    for (int ni = 0; ni < NI; ++ni)
#pragma unroll
      for (int r = 0; r < 4; ++r) {
        int m = tm + wm * PM + mi * 16 + g * 4 + r;
        int n = tn + wn * PN + ni * 16 + r15;
        float v = acc[mi][ni][r];
        if (OUTF32) Cf[(size_t)m * ldc + n] = v + bias[n];
        else        Cb[(size_t)m * ldc + n] = f2bf(v);
      }
}

// ---------------- flash attention: 4 waves x 2 q-strips, 2 blocks/CU --------------
// QK:  [B*S][4096] bf16 rows = {Q[h][d], K_scaled[h][d]}  (K pre-scaled by C2)
// VtG: [2048][4096] bf16 = V^T, row (h*128+d), col (b*2048+s)
// O:   [B*S][2048] bf16
// R17's 2-strip wave (kf/af read once, feed 2 MFMAs) kept verbatim; block shrunk
// to 4 waves / 256 threads / QBLK=128 -> grid 512 -> TWO desynced blocks per CU
// (same per-CU LDS traffic + wave count, but unsynchronized barriers let block A's
// stage/softmax overlap block B's MFMA). Staging = R4-proven 256-thread vmcnt(8)
// ledger; q-map/swizzle = R8-proven 512-wg map.
__global__ __launch_bounds__(256, 2) void attn_kernel(const u16* __restrict__ QK,
                                                      const u16* __restrict__ VtG,
                                                      u16* __restrict__ O) {
  __shared__ alignas(16) u16 Ks[2][64 * 128];   // 16KB each
  __shared__ alignas(16) u16 Vs[2][128 * 64];   // 16KB each

  const int tid = threadIdx.x, lane = tid & 63, wave = tid >> 6;  // wave 0..3
  const int r15 = lane & 15, g = lane >> 4;

  const int orig = (blockIdx.z * 16 + blockIdx.y) * 16 + blockIdx.x;  // 512 wgs
  const int wg = (orig & 7) * 64 + (orig >> 3);
  const int qb = wg & 15, h = (wg >> 4) & 15, b = wg >> 8;

  const u16* Qp = QK + (size_t)b * 2048 * 4096 + h * 128;
  const u16* Kp = Qp + 2048;
  const u16* Vp = VtG + (size_t)(h * 128) * 4096 + b * 2048;

  // Q fragments for both strips; strip s rows: qb*128 + wave*32 + s*16 + r15
  const int qrow0 = qb * 128 + wave * 32 + r15;
  bf16x8 qf[2][4];
#pragma unroll
  for (int s = 0; s < 2; ++s)
#pragma unroll
    for (int kc = 0; kc < 4; ++kc)
      qf[s][kc] = *(const bf16x8*)(Qp + (size_t)(qrow0 + s * 16) * 4096 +
                                   kc * 32 + g * 8);
  asm volatile("s_waitcnt vmcnt(0)" ::: "memory");

  // staging: 1024 chunks K + 1024 chunks V over 256 threads (4 each)
  int koff[4], voff[4];
#pragma unroll
  for (int i = 0; i < 4; ++i) {
    int c = i * 256 + tid;                     // 0..1023
    int kr = c >> 4, kj = c & 15;
    koff[i] = kr * 4096 + (kj ^ (kr & 7)) * 8;
    int vr = c >> 3, vj = c & 7;
    voff[i] = vr * 4096 + (vj ^ (vr & 7)) * 8;
  }
  const int sw = r15 & 7;

  f32x4 oacc[2][8] = {};
  float m[2] = {-1e30f, -1e30f}, l[2] = {0.f, 0.f};

  // prologue: stage tile 0 (8 loads/thread in flight)
#pragma unroll
  for (int i = 0; i < 4; ++i) {
    gload_lds16(Kp + koff[i], (char*)Ks[0] + (i * 4 + wave) * 1024);
    gload_lds16(Vp + voff[i], (char*)Vs[0] + (i * 4 + wave) * 1024);
  }

  for (int t = 0; t < 32; ++t) {
    const int cur = t & 1;
    if (t < 31) {
      const size_t kv0n = (size_t)(t + 1) * 64;
#pragma unroll
      for (int i = 0; i < 4; ++i) {
        gload_lds16(Kp + kv0n * 4096 + koff[i], (char*)Ks[cur ^ 1] + (i * 4 + wave) * 1024);
        gload_lds16(Vp + kv0n + voff[i], (char*)Vs[cur ^ 1] + (i * 4 + wave) * 1024);
      }
      wait_vmcnt<8>();                         // drain tile t's 8, keep t+1 in flight
    } else {
      wait_vmcnt<0>();
    }
    __builtin_amdgcn_s_barrier();
    __builtin_amdgcn_sched_barrier(0);

    // S^T = K_scaled · Q^T for BOTH strips; kf read once, used twice
    f32x4 sacc[2][4] = {};
    __builtin_amdgcn_s_setprio(1);
#pragma unroll
    for (int tt = 0; tt < 4; ++tt) {
      const int krow = tt * 16 + r15;
#pragma unroll
      for (int kc = 0; kc < 4; ++kc) {
        bf16x8 kf = *(const bf16x8*)((const char*)Ks[cur] + krow * 256 +
                                     (((kc * 4 + g) ^ sw) << 4));
        sacc[0][tt] = __builtin_amdgcn_mfma_f32_16x16x32_bf16(kf, qf[0][kc], sacc[0][tt], 0, 0, 0);
        sacc[1][tt] = __builtin_amdgcn_mfma_f32_16x16x32_bf16(kf, qf[1][kc], sacc[1][tt], 0, 0, 0);
      }
    }
    __builtin_amdgcn_s_setprio(0);

    // online softmax per strip (proven sequence, strip-indexed)
    u32 pk[2][4][2];
#pragma unroll
    for (int s = 0; s < 2; ++s) {
      float mx = fmaxf(fmaxf(sacc[s][0][0], sacc[s][0][1]),
                       fmaxf(sacc[s][0][2], sacc[s][0][3]));
#pragma unroll
      for (int tt = 1; tt < 4; ++tt)
#pragma unroll
        for (int r = 0; r < 4; ++r) mx = fmaxf(mx, sacc[s][tt][r]);
      mx = fmaxf(mx, __shfl_xor(mx, 16));
      mx = fmaxf(mx, __shfl_xor(mx, 32));

      if (!__all(mx - m[s] <= 8.0f)) {         // defer-max
        float mn = fmaxf(m[s], mx);
        float alpha = __builtin_amdgcn_exp2f(m[s] - mn);
#pragma unroll
        for (int dt = 0; dt < 8; ++dt) oacc[s][dt] *= alpha;
        l[s] *= alpha;
        m[s] = mn;
      }

      float rs = 0.f;
#pragma unroll
      for (int tt = 0; tt < 4; ++tt)
#pragma unroll
        for (int w = 0; w < 2; ++w) {
          float p0 = __builtin_amdgcn_exp2f(sacc[s][tt][2 * w] - m[s]);
          float p1 = __builtin_amdgcn_exp2f(sacc[s][tt][2 * w + 1] - m[s]);
          rs += p0 + p1;
          pk[s][tt][w] = cvtpk_bf16(p0, p1);
        }
      rs += __shfl_xor(rs, 16);
      rs += __shfl_xor(rs, 32);
      l[s] += rs;
    }

    // O^T += V^T · P^T for BOTH strips; af read once, used twice
    __builtin_amdgcn_s_setprio(1);
#pragma unroll
    for (int dt = 0; dt < 8; ++dt) {
      const int d = dt * 16 + r15;
      const char* vrow = (const char*)Vs[cur] + d * 128 + 8 * (g & 1);
      const int vsw = d & 7;
#pragma unroll
      for (int kh = 0; kh < 2; ++kh) {
        union { u32 u4[4]; bf16x8 v; } af, b0, b1;
        *(u32x2*)&af.u4[0] = *(const u32x2*)(vrow + (((kh * 4 + (g >> 1)) ^ vsw) << 4));
        *(u32x2*)&af.u4[2] = *(const u32x2*)(vrow + (((kh * 4 + 2 + (g >> 1)) ^ vsw) << 4));
        b0.u4[0] = pk[0][2 * kh][0];     b0.u4[1] = pk[0][2 * kh][1];
        b0.u4[2] = pk[0][2 * kh + 1][0]; b0.u4[3] = pk[0][2 * kh + 1][1];
        b1.u4[0] = pk[1][2 * kh][0];     b1.u4[1] = pk[1][2 * kh][1];
        b1.u4[2] = pk[1][2 * kh + 1][0]; b1.u4[3] = pk[1][2 * kh + 1][1];
        oacc[0][dt] = __builtin_amdgcn_mfma_f32_16x16x32_bf16(af.v, b0.v, oacc[0][dt], 0, 0, 0);
        oacc[1][dt] = __builtin_amdgcn_mfma_f32_16x16x32_bf16(af.v, b1.v, oacc[1][dt], 0, 0, 0);
      }
    }
    __builtin_amdgcn_s_setprio(0);

    __builtin_amdgcn_s_barrier();              // all waves done with buf[cur]
  }

  // epilogue per strip
#pragma unroll
  for (int s = 0; s < 2; ++s) {
    const float inv = 1.0f / l[s];
    u16* Ob = O + ((size_t)(b * 2048 + qrow0 + s * 16)) * 2048 + h * 128;
#pragma unroll
    for (int dt = 0; dt < 8; ++dt) {
      u32x2 pair;
      pair[0] = cvtpk_bf16(oacc[s][dt][0] * inv, oacc[s][dt][1] * inv);
      pair[1] = cvtpk_bf16(oacc[s][dt][2] * inv, oacc[s][dt][3] * inv);
      *(u32x2*)(Ob + dt * 16 + 4 * g) = pair;
    }
  }
}

// ---------------- host ----------------
extern "C" void kernel_launch(void* const* d_in, const int* in_sizes, int n_in,
                              void* d_out, int out_size, void* d_ws, size_t ws_size,
                              hipStream_t stream) {
  const float* x  = (const float*)d_in[0];
  const float* Wq = (const float*)d_in[1];
  const float* Wk = (const float*)d_in[2];
  const float* Wv = (const float*)d_in[3];
  const float* Wo = (const float*)d_in[4];
  const float* bo = (const float*)d_in[5];
  float* out = (float*)d_out;

  char* ws = (char*)d_ws;
  u16* xb    = (u16*)ws;                               // 16 MiB (reused as attn O)
  u16* WqkvT = (u16*)(ws + (size_t)16 * 1024 * 1024);  // 24 MiB [6144][2048]
  u16* WoT   = (u16*)(ws + (size_t)40 * 1024 * 1024);  // 8 MiB  [2048][2048]
  u16* QK    = (u16*)(ws + (size_t)48 * 1024 * 1024);  // 32 MiB [4096][4096]
  u16* VtG   = (u16*)(ws + (size_t)80 * 1024 * 1024);  // 16 MiB [2048][4096]
  u16* Oattn = xb;

  const float C2 = 0.12753102f;   // (1/sqrt(128)) * log2(e), folded into Wk

  cast_x_kernel<<<4096, 256, 0, stream>>>(x, xb);

  TC4 p;
  p.W[0] = Wq; p.W[1] = Wk; p.W[2] = Wv; p.W[3] = Wo;
  p.D[0] = WqkvT;
  p.D[1] = WqkvT + (size_t)2048 * 2048;
  p.D[2] = WqkvT + (size_t)4096 * 2048;
  p.D[3] = WoT;
  p.s[0] = 1.0f; p.s[1] = C2; p.s[2] = 1.0f; p.s[3] = 1.0f;
  transcast4<<<dim3(64, 64, 4), dim3(32, 8), 0, stream>>>(p);

  // QK = xb @ [Wq|Wk_scaled]   (M=4096, N=4096, K=2048), 256x256 tiles, 256 wgs
  gemm256<0, 256, 256, 2, 4><<<dim3(16, 16), 512, 0, stream>>>(
      xb, WqkvT, nullptr, QK, nullptr, 4096, 4096, 2048, 2048, 2048, 4096);
  // V^T = Wv^T @ x^T    (M=2048, N=4096, K=2048), 128x256 tiles, 256 wgs
  gemm256<0, 128, 256, 2, 4><<<dim3(16, 16), 512, 0, stream>>>(
      WqkvT + (size_t)4096 * 2048, xb, nullptr, VtG, nullptr,
      2048, 4096, 2048, 2048, 2048, 4096);
  // attention: 128 q-rows per block, 512 blocks of 256 threads (2 strips/wave)
  attn_kernel<<<dim3(16, 16, 2), 256, 0, stream>>>(QK, VtG, Oattn);
  // out = O @ Wo + bo   (M=4096, N=2048, K=2048), 256x128 tiles, 256 wgs
  gemm256<1, 256, 128, 4, 2><<<dim3(16, 16), 512, 0, stream>>>(
      Oattn, WoT, out, nullptr, bo, 4096, 2048, 2048, 2048, 2048, 2048);
}